// Round 7
// baseline (96.645 us; speedup 1.0000x reference)
//
#include <hip/hip_runtime.h>

// Gaussian VQ forward, split-bf16 MFMA. R3-validated primitives only;
// occupancy fix: 1024-thread blocks, wave-halves split the codebook.
// bs=64, dim_z=64, W=H=32 -> N=65536 rows, K=1024 codes, D=64.
//
// ws layout (bytes) — identical to R3 (validated):
//   [0    ..  511] : 64 (kld_discrete, kld_continuous) partial pairs (float)
//   [512  .. 4607] : cnorm[1024] fp32
//   [4608 .. 8703] : counts[1024] uint
//   [8704 ..     ] : cb_hi bf16[1024][64]  (131072 B)
//   [139776 ..   ] : cb_lo bf16[1024][64]  (131072 B)
#define WS_CNORM_B  512
#define WS_COUNTS_B 4608
#define WS_CBHI_B   8704
#define WS_CBLO_B   139776
#define WS_ZERO_B   8704

typedef __attribute__((ext_vector_type(8))) short short8;
typedef __attribute__((ext_vector_type(4))) float f32x4;

__device__ __forceinline__ unsigned short f2bf(float x) {
  unsigned u = __builtin_bit_cast(unsigned, x);
  u += 0x7fffu + ((u >> 16) & 1u);
  return (unsigned short)(u >> 16);
}
__device__ __forceinline__ float bf2f(unsigned short h) {
  unsigned u = ((unsigned)h) << 16;
  return __builtin_bit_cast(float, u);
}
__device__ __forceinline__ int qw(int r, int d) {
  return (r << 6) | (d ^ (r & 31));
}

// ---- prep: codebook -> bf16 hi/lo splits + ||c||^2 (verbatim R3) ----
__global__ __launch_bounds__(256) void vq_prep(const float* __restrict__ cb,
                                               char* __restrict__ ws) {
  int tid = blockIdx.x * 256 + threadIdx.x;
  int k = tid >> 6, d = threadIdx.x & 63;
  float v = cb[tid];
  unsigned short hi = f2bf(v);
  unsigned short lo = f2bf(v - bf2f(hi));
  ((unsigned short*)(ws + WS_CBHI_B))[tid] = hi;
  ((unsigned short*)(ws + WS_CBLO_B))[tid] = lo;
  float s = v * v;
  #pragma unroll
  for (int o = 32; o > 0; o >>= 1) s += __shfl_down(s, o);
  if (d == 0) ((float*)(ws + WS_CNORM_B))[k] = s;
}

// ---- main ----
// 512 blocks x 1024 threads (16 waves). Block owns 128 rows.
// Wave wv: rowgrp = wv&7 -> rows rowgrp*16..+15; half = wv>>3 -> codes
// half*512..+511 in 8 chunks of 64 (per-half LDS double-buffer).
// LDS (bytes):
//   [0, 65536)       buf[half][parity] 4 x 16 KB (hi 8K | lo 8K each,
//                    swizzled). z hi/lo staging uses [0,32768) in prologue;
//                    fp32 gather buffer reuses [0,32768) in epilogue.
//   [65536, 72704)   state: 2 halves x 128 rows x {m,S1,S2,b1v,b2v,k1,k2} 28 B
//   [72704, 73216)   fidx[128]
//   [73216, 73232)   redb[4]
#define ST_OFF   65536
#define FIDX_OFF 72704
#define REDB_OFF 73216

__global__ __launch_bounds__(1024) void vq_main(const float* __restrict__ z,
                                                const float* __restrict__ cb,
                                                const float* __restrict__ var_q,
                                                char* __restrict__ ws,
                                                float* __restrict__ out) {
  __shared__ __align__(16) char smem[73248];

  const int t = threadIdx.x;
  const int b = blockIdx.x;
  const int bb = b >> 3, p0 = (b & 7) << 7;
  const int l = t & 63, wv = t >> 6;
  const int lg = l >> 4, lr = l & 15;
  const int half = wv >> 3, rowgrp = wv & 7;
  const int th = t & 511;
  const float w = 0.5f / fmaxf(var_q[0], 1e-10f);
  const float w2 = 2.f * w;
  const float nw = -w;

  // ---- stage z -> [0,16384) hi, [16384,32768) lo, swizzled [p][d] ----
  for (int i = 0; i < 4; ++i) {
    int idx = t + i * 1024;            // 4096 u32 slots: p(128) x d2(32)
    int d2 = idx >> 7, p = idx & 127;
    float v0 = z[bb * 65536 + (2 * d2) * 1024 + p0 + p];
    float v1 = z[bb * 65536 + (2 * d2 + 1) * 1024 + p0 + p];
    unsigned short h0 = f2bf(v0), h1 = f2bf(v1);
    unsigned short o0 = f2bf(v0 - bf2f(h0)), o1 = f2bf(v1 - bf2f(h1));
    int byte = (p * 128 + d2 * 4) ^ ((p & 7) << 4);
    *(unsigned*)(smem + byte) = ((unsigned)h1 << 16) | h0;
    *(unsigned*)(smem + 16384 + byte) = ((unsigned)o1 << 16) | o0;
  }
  __syncthreads();

  // ---- A fragments for this wave's 16 rows (verbatim R3 pattern) ----
  short8 a_hi[2], a_lo[2];
  {
    int row = rowgrp * 16 + lr;
    #pragma unroll
    for (int ks = 0; ks < 2; ++ks) {
      int byte = (row * 128 + ks * 64 + lg * 16) ^ ((row & 7) << 4);
      a_hi[ks] = *(const short8*)(smem + byte);
      a_lo[ks] = *(const short8*)(smem + 16384 + byte);
    }
  }
  __syncthreads();  // z reads done; buffers free for chunk staging

  // ---- prologue: each half stages its chunk 0 ----
  const char* cbh = ws + WS_CBHI_B + half * 65536;
  const char* cbl = ws + WS_CBLO_B + half * 65536;
  char* bufbase = smem + half * 32768;
  const int wdst = (th * 16) ^ (((th >> 3) & 7) << 4);  // swizzled dst in 8KB
  {
    f32x4 rh = *(const f32x4*)(cbh + th * 16);
    f32x4 rl = *(const f32x4*)(cbl + th * 16);
    *(f32x4*)(bufbase + wdst) = rh;
    *(f32x4*)(bufbase + 8192 + wdst) = rl;
  }
  __syncthreads();

  // per-lane state: 4 rows (row = rowgrp*16 + lg*4 + j), codes of this half
  float m[4], S1[4], S2[4], b1v[4], b2v[4];
  int k1[4], k2[4], kk[4];
  #pragma unroll
  for (int j = 0; j < 4; ++j) {
    m[j] = -1e30f; S1[j] = 0.f; S2[j] = 0.f;
    b1v[j] = -1e30f; b2v[j] = -1e30f; k1[j] = 0; k2[j] = 0;
  }
  #pragma unroll
  for (int ct = 0; ct < 4; ++ct) kk[ct] = half * 512 + ct * 16 + lr;

  for (int ch = 0; ch < 8; ++ch) {
    char* cur = bufbase + (ch & 1) * 16384;
    char* nxt = bufbase + ((ch + 1) & 1) * 16384;
    f32x4 rh, rl;
    const bool pf = ch < 7;
    if (pf) {
      rh = *(const f32x4*)(cbh + (ch + 1) * 8192 + th * 16);
      rl = *(const f32x4*)(cbl + (ch + 1) * 8192 + th * 16);
    }
    const float* cn = (const float*)(ws + WS_CNORM_B) + half * 512 + ch * 64;
    float cn2[4];
    #pragma unroll
    for (int ct = 0; ct < 4; ++ct) cn2[ct] = nw * cn[ct * 16 + lr];

    f32x4 acc[4] = {};
    #pragma unroll
    for (int ct = 0; ct < 4; ++ct) {
      #pragma unroll
      for (int ks = 0; ks < 2; ++ks) {
        int cr = ct * 16 + lr;
        int byte = (cr * 128 + ks * 64 + lg * 16) ^ ((cr & 7) << 4);
        short8 bh = *(const short8*)(cur + byte);
        short8 bo = *(const short8*)(cur + 8192 + byte);
        acc[ct] = __builtin_amdgcn_mfma_f32_16x16x32_bf16(a_hi[ks], bh, acc[ct], 0, 0, 0);
        acc[ct] = __builtin_amdgcn_mfma_f32_16x16x32_bf16(a_lo[ks], bh, acc[ct], 0, 0, 0);
        acc[ct] = __builtin_amdgcn_mfma_f32_16x16x32_bf16(a_hi[ks], bo, acc[ct], 0, 0, 0);
      }
    }

    // epilogue: verbatim R3 (online max, __expf, branchless top-2)
    #pragma unroll
    for (int j = 0; j < 4; ++j) {
      float lv[4];
      #pragma unroll
      for (int ct = 0; ct < 4; ++ct) lv[ct] = fmaf(acc[ct][j], w2, cn2[ct]);
      float lm = fmaxf(fmaxf(lv[0], lv[1]), fmaxf(lv[2], lv[3]));
      float mn = fmaxf(m[j], lm);
      float sc = __expf(m[j] - mn);
      S1[j] *= sc; S2[j] *= sc; m[j] = mn;
      #pragma unroll
      for (int ct = 0; ct < 4; ++ct) {
        float e = __expf(lv[ct] - mn);
        S1[j] += e;
        S2[j] = fmaf(lv[ct], e, S2[j]);
        bool g1 = lv[ct] > b1v[j];
        bool g2 = lv[ct] > b2v[j];
        int kc = kk[ct];
        k2[j] = g2 ? kc : k2[j];
        k2[j] = g1 ? k1[j] : k2[j];
        b2v[j] = fmaxf(b2v[j], fminf(b1v[j], lv[ct]));
        k1[j] = g1 ? kc : k1[j];
        b1v[j] = fmaxf(b1v[j], lv[ct]);
      }
    }
    #pragma unroll
    for (int ct = 0; ct < 4; ++ct) kk[ct] += 64;

    if (pf) {
      *(f32x4*)(nxt + wdst) = rh;
      *(f32x4*)(nxt + 8192 + wdst) = rl;
    }
    __syncthreads();
  }

  // ---- merge the 16 code-columns within each wave (verbatim R3) ----
  #pragma unroll
  for (int st = 1; st < 16; st <<= 1) {
    #pragma unroll
    for (int j = 0; j < 4; ++j) {
      float om = __shfl_xor(m[j], st);
      float o1 = __shfl_xor(S1[j], st);
      float o2 = __shfl_xor(S2[j], st);
      float ov1 = __shfl_xor(b1v[j], st);
      float ov2 = __shfl_xor(b2v[j], st);
      int ok1 = __shfl_xor(k1[j], st);
      int ok2 = __shfl_xor(k2[j], st);
      float mn = fmaxf(m[j], om);
      float sa = __expf(m[j] - mn), sb = __expf(om - mn);
      S1[j] = sa * S1[j] + sb * o1;
      S2[j] = sa * S2[j] + sb * o2;
      m[j] = mn;
      bool ob = (ov1 > b1v[j]) || (ov1 == b1v[j] && ok1 < k1[j]);
      if (ob) {
        bool m2nd = (b1v[j] > ov2) || (b1v[j] == ov2 && k1[j] < ok2);
        float nv2 = m2nd ? b1v[j] : ov2;
        int nk2 = m2nd ? k1[j] : ok2;
        b1v[j] = ov1; k1[j] = ok1; b2v[j] = nv2; k2[j] = nk2;
      } else if ((ov1 > b2v[j]) || (ov1 == b2v[j] && ok1 < k2[j])) {
        b2v[j] = ov1; k2[j] = ok1;
      }
    }
  }

  // ---- per-half state write: {m,S1,S2,b1v,b2v,k1,k2} 28 B/row ----
  if (lr == 0) {
    #pragma unroll
    for (int j = 0; j < 4; ++j) {
      int r = rowgrp * 16 + lg * 4 + j;
      float* p = (float*)(smem + ST_OFF + half * 3584 + r * 28);
      p[0] = m[j]; p[1] = S1[j]; p[2] = S2[j]; p[3] = b1v[j]; p[4] = b2v[j];
      ((int*)p)[5] = k1[j]; ((int*)p)[6] = k2[j];
    }
  }
  __syncthreads();

  // ---- per-row tail: cross-half merge + exact fp32 rescore of top-2 ----
  int* fidx = (int*)(smem + FIDX_OFF);
  float* redb = (float*)(smem + REDB_OFF);
  float rowent = 0.f, d2min = 0.f;
  if (t < 128) {
    const float* pA = (const float*)(smem + ST_OFF + t * 28);
    const float* pB = (const float*)(smem + ST_OFF + 3584 + t * 28);
    float M0 = pA[0], S10 = pA[1], S20 = pA[2], V10 = pA[3], V20 = pA[4];
    int K10 = ((const int*)pA)[5], K20 = ((const int*)pA)[6];
    float M1 = pB[0], S11 = pB[1], S21 = pB[2], V11 = pB[3], V21 = pB[4];
    int K11 = ((const int*)pB)[5], K21 = ((const int*)pB)[6];
    float mn = fmaxf(M0, M1);
    float sa = __expf(M0 - mn), sb = __expf(M1 - mn);
    float s1 = sa * S10 + sb * S11;
    float s2 = sa * S20 + sb * S21;
    // top-2 of the two sorted pairs {A1,A2} x {B1,B2}
    bool og = (V11 > V10) || (V11 == V10 && K11 < K10);
    float l1v = og ? V10 : V11; int l1k = og ? K10 : K11;
    float w2v = og ? V21 : V20; int w2k = og ? K21 : K20;
    int ka = og ? K11 : K10;
    bool sg = (l1v > w2v) || (l1v == w2v && l1k < w2k);
    int kb = sg ? l1k : w2k;
    rowent = (s2 - mn * s1) / s1 - __logf(s1);
    const float* zp = z + bb * 65536 + p0 + t;
    const float* c1p = cb + ka * 64;
    const float* c2p = cb + kb * 64;
    float zn = 0.f, d1 = 0.f, d2 = 0.f;
    #pragma unroll 4
    for (int d4 = 0; d4 < 16; ++d4) {
      f32x4 ca = *(const f32x4*)(c1p + d4 * 4);
      f32x4 cc = *(const f32x4*)(c2p + d4 * 4);
      #pragma unroll
      for (int e = 0; e < 4; ++e) {
        float v = zp[(d4 * 4 + e) * 1024];
        zn = fmaf(v, v, zn);
        d1 = fmaf(v, ca[e], d1);
        d2 = fmaf(v, cc[e], d2);
      }
    }
    const float* cnf = (const float*)(ws + WS_CNORM_B);
    float da = zn + cnf[ka] - 2.f * d1;
    float db = zn + cnf[kb] - 2.f * d2;
    int kwin; float dwin;
    if (da < db || (da == db && ka < kb)) { kwin = ka; dwin = da; }
    else { kwin = kb; dwin = db; }
    fidx[t] = kwin;
    d2min = dwin;
    atomicAdd((unsigned*)(ws + WS_COUNTS_B) + kwin, 1u);
  }
  #pragma unroll
  for (int o = 32; o > 0; o >>= 1) {
    rowent += __shfl_down(rowent, o);
    d2min += __shfl_down(d2min, o);
  }
  if (t < 128 && l == 0) { redb[wv * 2] = rowent; redb[wv * 2 + 1] = d2min; }
  __syncthreads();
  if (t == 0) {
    float pd = redb[0] + redb[2];
    float pc = redb[1] + redb[3];
    float* wsf = (float*)ws;
    int slot = b & 63;
    atomicAdd(&wsf[slot * 2], pd);
    atomicAdd(&wsf[slot * 2 + 1], pc);
  }
  __syncthreads();

  // ---- gather chosen codes via LDS (fp32), write transposed coalesced ----
  float* zl = (float*)smem;  // [0,32768) dead now
  for (int i = 0; i < 8; ++i) {
    int idx = t + i * 1024;
    int r = idx >> 6, d = idx & 63;
    zl[qw(r, d)] = cb[fidx[r] * 64 + d];
  }
  __syncthreads();
  float* outz = out + bb * 65536 + p0;
  #pragma unroll
  for (int i = 0; i < 2; ++i) {
    int q = t + i * 1024;
    int d = q >> 5, rq = q & 31, r = rq << 2;
    f32x4 v;
    v.x = zl[qw(r + 0, d)];
    v.y = zl[qw(r + 1, d)];
    v.z = zl[qw(r + 2, d)];
    v.w = zl[qw(r + 3, d)];
    *(f32x4*)&outz[d * 1024 + r] = v;
  }
}

__global__ __launch_bounds__(1024) void vq_finalize(const float* __restrict__ var_q,
                                                    char* __restrict__ ws,
                                                    float* __restrict__ out) {
  __shared__ float red[48];
  int t = threadIdx.x;
  const unsigned* counts = (const unsigned*)(ws + WS_COUNTS_B);
  const float* wsf = (const float*)ws;
  float avg = (float)counts[t] * (1.0f / 65536.0f);
  float term = avg * __logf(avg + 1e-7f);
  float pd = 0.f, pc = 0.f;
  if (t < 64) { pd = wsf[2 * t]; pc = wsf[2 * t + 1]; }
  #pragma unroll
  for (int o = 32; o > 0; o >>= 1) {
    term += __shfl_down(term, o);
    pd += __shfl_down(pd, o);
    pc += __shfl_down(pc, o);
  }
  int wv = t >> 6, lane = t & 63;
  if (lane == 0) { red[wv * 3] = term; red[wv * 3 + 1] = pd; red[wv * 3 + 2] = pc; }
  __syncthreads();
  if (t == 0) {
    float ts = 0.f, ps = 0.f, cs = 0.f;
    #pragma unroll
    for (int i = 0; i < 16; ++i) {
      ts += red[i * 3]; ps += red[i * 3 + 1]; cs += red[i * 3 + 2];
    }
    float w = 0.5f / fmaxf(var_q[0], 1e-10f);
    out[4194304] = ps / 64.f + w * cs / 64.f;
    out[4194305] = __expf(-ts);
  }
}

extern "C" void kernel_launch(void* const* d_in, const int* in_sizes, int n_in,
                              void* d_out, int out_size, void* d_ws, size_t ws_size,
                              hipStream_t stream) {
  const float* z = (const float*)d_in[0];
  const float* vq = (const float*)d_in[1];
  const float* cb = (const float*)d_in[2];
  float* out = (float*)d_out;
  char* ws = (char*)d_ws;

  hipMemsetAsync(d_ws, 0, WS_ZERO_B, stream);
  vq_prep<<<256, 256, 0, stream>>>(cb, ws);
  vq_main<<<512, 1024, 0, stream>>>(z, cb, vq, ws, out);
  vq_finalize<<<1, 1024, 0, stream>>>(vq, ws, out);
}

// Round 10
// 84.670 us; speedup vs baseline: 1.1414x; 1.1414x over previous
//
#include <hip/hip_runtime.h>

// Gaussian VQ forward, split-bf16 MFMA. R9 structure with the bitpack fix:
//  - 128-code chunks (8 barriers), 2x32KB LDS double-buffer
//  - packed value|code top-2: low 10 mantissa bits CLEARED then code OR'd in
//  - online-max rescale (R3-validated numerics), exact fp32 top-2 rescore
// bs=64, dim_z=64, W=H=32 -> N=65536 rows, K=1024 codes, D=64.
//
// ws layout (bytes) — identical to R3 (validated):
//   [0    ..  511] : 64 (kld_discrete, kld_continuous) partial pairs (float)
//   [512  .. 4607] : cnorm[1024] fp32
//   [4608 .. 8703] : counts[1024] uint
//   [8704 ..     ] : cb_hi bf16[1024][64]  (131072 B)
//   [139776 ..   ] : cb_lo bf16[1024][64]  (131072 B)
#define WS_CNORM_B  512
#define WS_COUNTS_B 4608
#define WS_CBHI_B   8704
#define WS_CBLO_B   139776
#define WS_ZERO_B   8704

typedef __attribute__((ext_vector_type(8))) short short8;
typedef __attribute__((ext_vector_type(4))) float f32x4;

__device__ __forceinline__ unsigned short f2bf(float x) {
  unsigned u = __builtin_bit_cast(unsigned, x);
  u += 0x7fffu + ((u >> 16) & 1u);
  return (unsigned short)(u >> 16);
}
__device__ __forceinline__ float bf2f(unsigned short h) {
  unsigned u = ((unsigned)h) << 16;
  return __builtin_bit_cast(float, u);
}
__device__ __forceinline__ int qw(int r, int d) {
  return (r << 6) | (d ^ (r & 31));
}

// ---- prep: codebook -> bf16 hi/lo splits + ||c||^2 (verbatim R3) ----
__global__ __launch_bounds__(256) void vq_prep(const float* __restrict__ cb,
                                               char* __restrict__ ws) {
  int tid = blockIdx.x * 256 + threadIdx.x;
  int k = tid >> 6, d = threadIdx.x & 63;
  float v = cb[tid];
  unsigned short hi = f2bf(v);
  unsigned short lo = f2bf(v - bf2f(hi));
  ((unsigned short*)(ws + WS_CBHI_B))[tid] = hi;
  ((unsigned short*)(ws + WS_CBLO_B))[tid] = lo;
  float s = v * v;
  #pragma unroll
  for (int o = 32; o > 0; o >>= 1) s += __shfl_down(s, o);
  if (d == 0) ((float*)(ws + WS_CNORM_B))[k] = s;
}

// LDS (bytes):
//   [0, 32768)      buf A: z hi/lo staging -> chunk buf -> fp32 gather buf
//   [32768, 65536)  buf B
//   [65536, 68096)  row state: 128 x {m, S1, S2, b1, b2} (20 B)
//   [68096, 68608)  fidx[128]
//   [68608, 68624)  redb[4]
#define ST_OFF   65536
#define FIDX_OFF 68096
#define REDB_OFF 68608

__global__ __launch_bounds__(512) void vq_main(const float* __restrict__ z,
                                               const float* __restrict__ cb,
                                               const float* __restrict__ var_q,
                                               char* __restrict__ ws,
                                               float* __restrict__ out) {
  __shared__ __align__(16) char smem[68624];

  const int t = threadIdx.x;
  const int b = blockIdx.x;          // 512 blocks, 128 rows each
  const int bb = b >> 3, p0 = (b & 7) << 7;
  const int l = t & 63, wv = t >> 6;
  const int lg = l >> 4, lr = l & 15;
  const float w = 0.5f / fmaxf(var_q[0], 1e-10f);
  const float w2 = 2.f * w;
  const float nw = -w;

  // ---- stage z -> [0,16K) hi, [16K,32K) lo, swizzled [p][d] (verbatim R3) ----
  for (int i = 0; i < 8; ++i) {
    int idx = t + i * 512;             // 4096 u32 slots: p(128) x d2(32)
    int d2 = idx >> 7, p = idx & 127;
    float v0 = z[bb * 65536 + (2 * d2) * 1024 + p0 + p];
    float v1 = z[bb * 65536 + (2 * d2 + 1) * 1024 + p0 + p];
    unsigned short h0 = f2bf(v0), h1 = f2bf(v1);
    unsigned short o0 = f2bf(v0 - bf2f(h0)), o1 = f2bf(v1 - bf2f(h1));
    int byte = (p * 128 + d2 * 4) ^ ((p & 7) << 4);
    *(unsigned*)(smem + byte) = ((unsigned)h1 << 16) | h0;
    *(unsigned*)(smem + 16384 + byte) = ((unsigned)o1 << 16) | o0;
  }
  __syncthreads();

  // ---- A fragments for this wave's 16 rows (verbatim R3) ----
  short8 a_hi[2], a_lo[2];
  {
    int row = wv * 16 + lr;
    #pragma unroll
    for (int ks = 0; ks < 2; ++ks) {
      int byte = (row * 128 + ks * 64 + lg * 16) ^ ((row & 7) << 4);
      a_hi[ks] = *(const short8*)(smem + byte);
      a_lo[ks] = *(const short8*)(smem + 16384 + byte);
    }
  }
  __syncthreads();  // z reads done; buffers free for chunk staging

  // ---- prologue: stage chunk 0 (128 codes, 32KB) into buf A ----
  const char* cbh = ws + WS_CBHI_B;
  const char* cbl = ws + WS_CBLO_B;
  const int wdst = (t * 16) ^ (((t >> 3) & 7) << 4);  // 16KB-half swizzle
  {
    f32x4 h0 = *(const f32x4*)(cbh + t * 16);
    f32x4 h1 = *(const f32x4*)(cbh + t * 16 + 8192);
    f32x4 l0 = *(const f32x4*)(cbl + t * 16);
    f32x4 l1 = *(const f32x4*)(cbl + t * 16 + 8192);
    *(f32x4*)(smem + wdst) = h0;
    *(f32x4*)(smem + (wdst + 8192)) = h1;
    *(f32x4*)(smem + 16384 + wdst) = l0;
    *(f32x4*)(smem + 16384 + (wdst + 8192)) = l1;
  }
  __syncthreads();

  // per-lane state: 4 rows (row = wv*16 + lg*4 + j).
  // b1/b2 PACKED: low 10 mantissa bits cleared, 10-bit code index OR'd in
  // (perturbation ~2^-13 relative; exact fp32 rescore arbitrates).
  float m[4], S1[4], S2[4], b1[4], b2[4];
  #pragma unroll
  for (int j = 0; j < 4; ++j) {
    m[j] = -1e30f; S1[j] = 0.f; S2[j] = 0.f; b1[j] = -1e30f; b2[j] = -1e30f;
  }

  const float* cnf = (const float*)(ws + WS_CNORM_B);

  for (int ch = 0; ch < 8; ++ch) {
    char* cur = smem + (ch & 1) * 32768;
    char* nxt = smem + ((ch + 1) & 1) * 32768;
    f32x4 rh0, rh1, rl0, rl1;
    const bool pf = ch < 7;
    if (pf) {  // prefetch next chunk into regs; latency hides under compute
      const char* sh = cbh + (ch + 1) * 16384 + t * 16;
      const char* sl = cbl + (ch + 1) * 16384 + t * 16;
      rh0 = *(const f32x4*)sh;  rh1 = *(const f32x4*)(sh + 8192);
      rl0 = *(const f32x4*)sl;  rl1 = *(const f32x4*)(sl + 8192);
    }
    float cn2[8];
    #pragma unroll
    for (int ct = 0; ct < 8; ++ct) cn2[ct] = nw * cnf[ch * 128 + ct * 16 + lr];

    f32x4 acc[8];
    #pragma unroll
    for (int ct = 0; ct < 8; ++ct) {
      f32x4 a = {};
      #pragma unroll
      for (int ks = 0; ks < 2; ++ks) {
        int cr = ct * 16 + lr;
        int byte = (cr * 128 + ks * 64 + lg * 16) ^ ((cr & 7) << 4);
        short8 bh = *(const short8*)(cur + byte);
        short8 bo = *(const short8*)(cur + 16384 + byte);
        a = __builtin_amdgcn_mfma_f32_16x16x32_bf16(a_hi[ks], bh, a, 0, 0, 0);
        a = __builtin_amdgcn_mfma_f32_16x16x32_bf16(a_lo[ks], bh, a, 0, 0, 0);
        a = __builtin_amdgcn_mfma_f32_16x16x32_bf16(a_hi[ks], bo, a, 0, 0, 0);
      }
      acc[ct] = a;
    }

    // epilogue: online-max rescale + packed fmax top-2 (mask-then-OR)
    #pragma unroll
    for (int j = 0; j < 4; ++j) {
      float lv[8];
      #pragma unroll
      for (int ct = 0; ct < 8; ++ct) lv[ct] = fmaf(acc[ct][j], w2, cn2[ct]);
      float lm = fmaxf(fmaxf(fmaxf(lv[0], lv[1]), fmaxf(lv[2], lv[3])),
                       fmaxf(fmaxf(lv[4], lv[5]), fmaxf(lv[6], lv[7])));
      float mn = fmaxf(m[j], lm);
      float sc = __expf(m[j] - mn);
      S1[j] *= sc; S2[j] *= sc; m[j] = mn;
      #pragma unroll
      for (int ct = 0; ct < 8; ++ct) {
        float x = lv[ct];
        unsigned ku = (unsigned)(ch * 128 + ct * 16 + lr);
        unsigned xb = (__builtin_bit_cast(unsigned, x) & ~1023u) | ku;
        float xp = __builtin_bit_cast(float, xb);
        float tm = fminf(b1[j], xp);
        b1[j] = fmaxf(b1[j], xp);
        b2[j] = fmaxf(b2[j], tm);
        float e = __expf(x - mn);
        S1[j] += e;
        S2[j] = fmaf(x, e, S2[j]);   // S2 = sum x * e^{x-m}
      }
    }

    if (pf) {
      *(f32x4*)(nxt + wdst) = rh0;
      *(f32x4*)(nxt + (wdst + 8192)) = rh1;
      *(f32x4*)(nxt + 16384 + wdst) = rl0;
      *(f32x4*)(nxt + 16384 + (wdst + 8192)) = rl1;
    }
    __syncthreads();
  }

  // ---- merge the 16 code-columns within each wave ----
  #pragma unroll
  for (int st = 1; st < 16; st <<= 1) {
    #pragma unroll
    for (int j = 0; j < 4; ++j) {
      float om = __shfl_xor(m[j], st);
      float o1 = __shfl_xor(S1[j], st);
      float o2 = __shfl_xor(S2[j], st);
      float ov1 = __shfl_xor(b1[j], st);
      float ov2 = __shfl_xor(b2[j], st);
      float mn = fmaxf(m[j], om);
      float sa = __expf(m[j] - mn), sb = __expf(om - mn);
      S1[j] = sa * S1[j] + sb * o1;
      S2[j] = sa * S2[j] + sb * o2;
      m[j] = mn;
      float nb1 = fmaxf(b1[j], ov1);
      float nb2 = fmaxf(fminf(b1[j], ov1), fmaxf(b2[j], ov2));
      b1[j] = nb1; b2[j] = nb2;
    }
  }

  // ---- state write: scalar stores, 20B stride ----
  float* stw = (float*)(smem + ST_OFF);
  if (lr == 0) {
    #pragma unroll
    for (int j = 0; j < 4; ++j) {
      int r = wv * 16 + lg * 4 + j;
      float* p = stw + r * 5;
      p[0] = m[j]; p[1] = S1[j]; p[2] = S2[j]; p[3] = b1[j]; p[4] = b2[j];
    }
  }
  __syncthreads();

  // ---- per-row tail: entropy + exact fp32 rescore of top-2 + histogram ----
  int* fidx = (int*)(smem + FIDX_OFF);
  float* redb = (float*)(smem + REDB_OFF);
  float rowent = 0.f, d2min = 0.f;
  if (t < 128) {
    const float* p = stw + t * 5;
    float mn = p[0], s1 = p[1], s2 = p[2];
    int ka = (int)(__builtin_bit_cast(unsigned, p[3]) & 1023u);
    int kb = (int)(__builtin_bit_cast(unsigned, p[4]) & 1023u);
    rowent = (s2 - mn * s1) / s1 - __logf(s1);
    const float* zp = z + bb * 65536 + p0 + t;
    const float* c1p = cb + ka * 64;
    const float* c2p = cb + kb * 64;
    float zn = 0.f, d1 = 0.f, d2 = 0.f;
    #pragma unroll 4
    for (int d4 = 0; d4 < 16; ++d4) {
      f32x4 ca = *(const f32x4*)(c1p + d4 * 4);
      f32x4 cc = *(const f32x4*)(c2p + d4 * 4);
      #pragma unroll
      for (int e = 0; e < 4; ++e) {
        float v = zp[(d4 * 4 + e) * 1024];
        zn = fmaf(v, v, zn);
        d1 = fmaf(v, ca[e], d1);
        d2 = fmaf(v, cc[e], d2);
      }
    }
    float da = zn + cnf[ka] - 2.f * d1;
    float db = zn + cnf[kb] - 2.f * d2;
    int kwin; float dwin;
    if (da < db || (da == db && ka < kb)) { kwin = ka; dwin = da; }
    else { kwin = kb; dwin = db; }
    fidx[t] = kwin;
    d2min = dwin;
    atomicAdd((unsigned*)(ws + WS_COUNTS_B) + kwin, 1u);
  }
  #pragma unroll
  for (int o = 32; o > 0; o >>= 1) {
    rowent += __shfl_down(rowent, o);
    d2min += __shfl_down(d2min, o);
  }
  if (t < 128 && l == 0) { redb[wv * 2] = rowent; redb[wv * 2 + 1] = d2min; }
  __syncthreads();
  if (t == 0) {
    float pd = redb[0] + redb[2];
    float pc = redb[1] + redb[3];
    float* wsf = (float*)ws;
    int slot = b & 63;
    atomicAdd(&wsf[slot * 2], pd);
    atomicAdd(&wsf[slot * 2 + 1], pc);
  }
  __syncthreads();

  // ---- gather chosen codes via LDS (fp32), write transposed coalesced ----
  float* zl = (float*)smem;  // buf A region, dead now
  for (int i = 0; i < 16; ++i) {
    int idx = t + i * 512;
    int r = idx >> 6, d = idx & 63;
    zl[qw(r, d)] = cb[fidx[r] * 64 + d];
  }
  __syncthreads();
  float* outz = out + bb * 65536 + p0;
  #pragma unroll
  for (int i = 0; i < 4; ++i) {
    int q = t + i * 512;
    int d = q >> 5, rq = q & 31, r = rq << 2;
    f32x4 v;
    v.x = zl[qw(r + 0, d)];
    v.y = zl[qw(r + 1, d)];
    v.z = zl[qw(r + 2, d)];
    v.w = zl[qw(r + 3, d)];
    *(f32x4*)&outz[d * 1024 + r] = v;
  }
}

__global__ __launch_bounds__(1024) void vq_finalize(const float* __restrict__ var_q,
                                                    char* __restrict__ ws,
                                                    float* __restrict__ out) {
  __shared__ float red[48];
  int t = threadIdx.x;
  const unsigned* counts = (const unsigned*)(ws + WS_COUNTS_B);
  const float* wsf = (const float*)ws;
  float avg = (float)counts[t] * (1.0f / 65536.0f);
  float term = avg * __logf(avg + 1e-7f);
  float pd = 0.f, pc = 0.f;
  if (t < 64) { pd = wsf[2 * t]; pc = wsf[2 * t + 1]; }
  #pragma unroll
  for (int o = 32; o > 0; o >>= 1) {
    term += __shfl_down(term, o);
    pd += __shfl_down(pd, o);
    pc += __shfl_down(pc, o);
  }
  int wv = t >> 6, lane = t & 63;
  if (lane == 0) { red[wv * 3] = term; red[wv * 3 + 1] = pd; red[wv * 3 + 2] = pc; }
  __syncthreads();
  if (t == 0) {
    float ts = 0.f, ps = 0.f, cs = 0.f;
    #pragma unroll
    for (int i = 0; i < 16; ++i) {
      ts += red[i * 3]; ps += red[i * 3 + 1]; cs += red[i * 3 + 2];
    }
    float w = 0.5f / fmaxf(var_q[0], 1e-10f);
    out[4194304] = ps / 64.f + w * cs / 64.f;
    out[4194305] = __expf(-ts);
  }
}

extern "C" void kernel_launch(void* const* d_in, const int* in_sizes, int n_in,
                              void* d_out, int out_size, void* d_ws, size_t ws_size,
                              hipStream_t stream) {
  const float* z = (const float*)d_in[0];
  const float* vq = (const float*)d_in[1];
  const float* cb = (const float*)d_in[2];
  float* out = (float*)d_out;
  char* ws = (char*)d_ws;

  hipMemsetAsync(d_ws, 0, WS_ZERO_B, stream);
  vq_prep<<<256, 256, 0, stream>>>(cb, ws);
  vq_main<<<512, 512, 0, stream>>>(z, cb, vq, ws, out);
  vq_finalize<<<1, 1024, 0, stream>>>(vq, ws, out);
}

// Round 11
// 75.917 us; speedup vs baseline: 1.2730x; 1.1153x over previous
//
#include <hip/hip_runtime.h>

// Gaussian VQ forward, split-bf16 MFMA. R10-validated math; new decomposition:
// 1024 blocks x 256 threads (4 waves), 64 rows/block, 64-code chunks ->
// 4 blocks/CU, 4-wave barrier domains (latency hiding via block-level overlap).
// bs=64, dim_z=64, W=H=32 -> N=65536 rows, K=1024 codes, D=64.
//
// ws layout (bytes) — identical to R3/R10 (validated):
//   [0    ..  511] : 64 (kld_discrete, kld_continuous) partial pairs (float)
//   [512  .. 4607] : cnorm[1024] fp32
//   [4608 .. 8703] : counts[1024] uint
//   [8704 ..     ] : cb_hi bf16[1024][64]  (131072 B)
//   [139776 ..   ] : cb_lo bf16[1024][64]  (131072 B)
#define WS_CNORM_B  512
#define WS_COUNTS_B 4608
#define WS_CBHI_B   8704
#define WS_CBLO_B   139776
#define WS_ZERO_B   8704

typedef __attribute__((ext_vector_type(8))) short short8;
typedef __attribute__((ext_vector_type(4))) float f32x4;

__device__ __forceinline__ unsigned short f2bf(float x) {
  unsigned u = __builtin_bit_cast(unsigned, x);
  u += 0x7fffu + ((u >> 16) & 1u);
  return (unsigned short)(u >> 16);
}
__device__ __forceinline__ float bf2f(unsigned short h) {
  unsigned u = ((unsigned)h) << 16;
  return __builtin_bit_cast(float, u);
}
__device__ __forceinline__ int qw(int r, int d) {
  return (r << 6) | (d ^ (r & 31));
}

// ---- prep: codebook -> bf16 hi/lo splits + ||c||^2 (verbatim R3/R10) ----
__global__ __launch_bounds__(256) void vq_prep(const float* __restrict__ cb,
                                               char* __restrict__ ws) {
  int tid = blockIdx.x * 256 + threadIdx.x;
  int k = tid >> 6, d = threadIdx.x & 63;
  float v = cb[tid];
  unsigned short hi = f2bf(v);
  unsigned short lo = f2bf(v - bf2f(hi));
  ((unsigned short*)(ws + WS_CBHI_B))[tid] = hi;
  ((unsigned short*)(ws + WS_CBLO_B))[tid] = lo;
  float s = v * v;
  #pragma unroll
  for (int o = 32; o > 0; o >>= 1) s += __shfl_down(s, o);
  if (d == 0) ((float*)(ws + WS_CNORM_B))[k] = s;
}

// LDS (bytes):
//   [0, 32768)      chunk dbuf (parity*16384; hi 8K | lo 8K each).
//                   Prologue: z hi [0,8192) / lo [8192,16384).
//                   Epilogue: fp32 gather buffer [0,16384).
//   [32768, 34048)  row state: 64 x {m, S1, S2, b1, b2} (20 B)
//   [34048, 34304)  fidx[64]
#define ST_OFF   32768
#define FIDX_OFF 34048

__global__ __launch_bounds__(256, 4) void vq_main(const float* __restrict__ z,
                                                  const float* __restrict__ cb,
                                                  const float* __restrict__ var_q,
                                                  char* __restrict__ ws,
                                                  float* __restrict__ out) {
  __shared__ __align__(16) char smem[34304];

  const int t = threadIdx.x;
  const int b = blockIdx.x;          // 1024 blocks, 64 rows each
  const int bb = b >> 4, p0 = (b & 15) << 6;
  const int l = t & 63, wv = t >> 6;           // 4 waves
  const int lg = l >> 4, lr = l & 15;
  const float w = 0.5f / fmaxf(var_q[0], 1e-10f);
  const float w2 = 2.f * w;
  const float nw = -w;

  // ---- stage z (64 rows) -> [0,8K) hi, [8K,16K) lo, swizzled [p][d] ----
  for (int i = 0; i < 8; ++i) {
    int idx = t + i * 256;             // 2048 u32 slots: p(64) x d2(32)
    int d2 = idx >> 6, p = idx & 63;
    float v0 = z[bb * 65536 + (2 * d2) * 1024 + p0 + p];
    float v1 = z[bb * 65536 + (2 * d2 + 1) * 1024 + p0 + p];
    unsigned short h0 = f2bf(v0), h1 = f2bf(v1);
    unsigned short o0 = f2bf(v0 - bf2f(h0)), o1 = f2bf(v1 - bf2f(h1));
    int byte = (p * 128 + d2 * 4) ^ ((p & 7) << 4);
    *(unsigned*)(smem + byte) = ((unsigned)h1 << 16) | h0;
    *(unsigned*)(smem + 8192 + byte) = ((unsigned)o1 << 16) | o0;
  }
  __syncthreads();

  // ---- A fragments: wave's 16 rows (row = wv*16 + lr) ----
  short8 a_hi[2], a_lo[2];
  {
    int row = wv * 16 + lr;
    #pragma unroll
    for (int ks = 0; ks < 2; ++ks) {
      int byte = (row * 128 + ks * 64 + lg * 16) ^ ((row & 7) << 4);
      a_hi[ks] = *(const short8*)(smem + byte);
      a_lo[ks] = *(const short8*)(smem + 8192 + byte);
    }
  }
  __syncthreads();  // z reads done; region becomes chunk dbuf

  // ---- prologue: stage chunk 0 (64 codes: 8KB hi + 8KB lo) into parity 0 ----
  const char* cbh = ws + WS_CBHI_B;
  const char* cbl = ws + WS_CBLO_B;
  {
    #pragma unroll
    for (int pas = 0; pas < 2; ++pas) {
      int o = t + pas * 256;
      int dst = (o * 16) ^ (((o >> 3) & 7) << 4);
      *(f32x4*)(smem + dst) = *(const f32x4*)(cbh + o * 16);
      *(f32x4*)(smem + 8192 + dst) = *(const f32x4*)(cbl + o * 16);
    }
  }
  __syncthreads();

  // per-lane state: 4 rows (row = wv*16 + lg*4 + j).
  // b1/b2 PACKED (R10-validated): low 10 mantissa bits cleared, code OR'd in.
  float m[4], S1[4], S2[4], b1[4], b2[4];
  #pragma unroll
  for (int j = 0; j < 4; ++j) {
    m[j] = -1e30f; S1[j] = 0.f; S2[j] = 0.f; b1[j] = -1e30f; b2[j] = -1e30f;
  }

  const float* cnf = (const float*)(ws + WS_CNORM_B);

  for (int ch = 0; ch < 16; ++ch) {
    char* cur = smem + (ch & 1) * 16384;
    char* nxt = smem + ((ch + 1) & 1) * 16384;
    f32x4 rh0, rh1, rl0, rl1;
    const bool pf = ch < 15;
    if (pf) {  // prefetch next chunk into regs; latency hides under compute
      const char* sh = cbh + (ch + 1) * 8192 + t * 16;
      const char* sl = cbl + (ch + 1) * 8192 + t * 16;
      rh0 = *(const f32x4*)sh;  rh1 = *(const f32x4*)(sh + 4096);
      rl0 = *(const f32x4*)sl;  rl1 = *(const f32x4*)(sl + 4096);
    }
    float cn2[4];
    #pragma unroll
    for (int ct = 0; ct < 4; ++ct) cn2[ct] = nw * cnf[ch * 64 + ct * 16 + lr];

    f32x4 acc[4];
    #pragma unroll
    for (int ct = 0; ct < 4; ++ct) {
      f32x4 a = {};
      #pragma unroll
      for (int ks = 0; ks < 2; ++ks) {
        int cr = ct * 16 + lr;
        int byte = (cr * 128 + ks * 64 + lg * 16) ^ ((cr & 7) << 4);
        short8 bh = *(const short8*)(cur + byte);
        short8 bo = *(const short8*)(cur + 8192 + byte);
        a = __builtin_amdgcn_mfma_f32_16x16x32_bf16(a_hi[ks], bh, a, 0, 0, 0);
        a = __builtin_amdgcn_mfma_f32_16x16x32_bf16(a_lo[ks], bh, a, 0, 0, 0);
        a = __builtin_amdgcn_mfma_f32_16x16x32_bf16(a_hi[ks], bo, a, 0, 0, 0);
      }
      acc[ct] = a;
    }

    // epilogue: online-max rescale + packed fmax top-2 (verbatim R10 math)
    #pragma unroll
    for (int j = 0; j < 4; ++j) {
      float lv[4];
      #pragma unroll
      for (int ct = 0; ct < 4; ++ct) lv[ct] = fmaf(acc[ct][j], w2, cn2[ct]);
      float lm = fmaxf(fmaxf(lv[0], lv[1]), fmaxf(lv[2], lv[3]));
      float mn = fmaxf(m[j], lm);
      float sc = __expf(m[j] - mn);
      S1[j] *= sc; S2[j] *= sc; m[j] = mn;
      #pragma unroll
      for (int ct = 0; ct < 4; ++ct) {
        float x = lv[ct];
        unsigned ku = (unsigned)(ch * 64 + ct * 16 + lr);
        unsigned xb = (__builtin_bit_cast(unsigned, x) & ~1023u) | ku;
        float xp = __builtin_bit_cast(float, xb);
        float tm = fminf(b1[j], xp);
        b1[j] = fmaxf(b1[j], xp);
        b2[j] = fmaxf(b2[j], tm);
        float e = __expf(x - mn);
        S1[j] += e;
        S2[j] = fmaf(x, e, S2[j]);   // S2 = sum x * e^{x-m}
      }
    }

    if (pf) {
      #pragma unroll
      for (int pas = 0; pas < 2; ++pas) {
        int o = t + pas * 256;
        int dst = (o * 16) ^ (((o >> 3) & 7) << 4);
        *(f32x4*)(nxt + dst) = pas ? rh1 : rh0;
        *(f32x4*)(nxt + 8192 + dst) = pas ? rl1 : rl0;
      }
    }
    __syncthreads();
  }

  // ---- merge the 16 code-columns within each wave (verbatim R10) ----
  #pragma unroll
  for (int st = 1; st < 16; st <<= 1) {
    #pragma unroll
    for (int j = 0; j < 4; ++j) {
      float om = __shfl_xor(m[j], st);
      float o1 = __shfl_xor(S1[j], st);
      float o2 = __shfl_xor(S2[j], st);
      float ov1 = __shfl_xor(b1[j], st);
      float ov2 = __shfl_xor(b2[j], st);
      float mn = fmaxf(m[j], om);
      float sa = __expf(m[j] - mn), sb = __expf(om - mn);
      S1[j] = sa * S1[j] + sb * o1;
      S2[j] = sa * S2[j] + sb * o2;
      m[j] = mn;
      float nb1 = fmaxf(b1[j], ov1);
      float nb2 = fmaxf(fminf(b1[j], ov1), fmaxf(b2[j], ov2));
      b1[j] = nb1; b2[j] = nb2;
    }
  }

  // ---- state write: 64 rows x 20 B ----
  float* stw = (float*)(smem + ST_OFF);
  if (lr == 0) {
    #pragma unroll
    for (int j = 0; j < 4; ++j) {
      int r = wv * 16 + lg * 4 + j;
      float* p = stw + r * 5;
      p[0] = m[j]; p[1] = S1[j]; p[2] = S2[j]; p[3] = b1[j]; p[4] = b2[j];
    }
  }
  __syncthreads();

  // ---- per-row tail (wave 0): entropy + exact fp32 top-2 rescore ----
  int* fidx = (int*)(smem + FIDX_OFF);
  float rowent = 0.f, d2min = 0.f;
  if (t < 64) {
    const float* p = stw + t * 5;
    float mn = p[0], s1 = p[1], s2 = p[2];
    int ka = (int)(__builtin_bit_cast(unsigned, p[3]) & 1023u);
    int kb = (int)(__builtin_bit_cast(unsigned, p[4]) & 1023u);
    rowent = (s2 - mn * s1) / s1 - __logf(s1);
    const float* zp = z + bb * 65536 + p0 + t;
    const float* c1p = cb + ka * 64;
    const float* c2p = cb + kb * 64;
    float zn = 0.f, d1 = 0.f, d2 = 0.f;
    #pragma unroll 4
    for (int d4 = 0; d4 < 16; ++d4) {
      f32x4 ca = *(const f32x4*)(c1p + d4 * 4);
      f32x4 cc = *(const f32x4*)(c2p + d4 * 4);
      #pragma unroll
      for (int e = 0; e < 4; ++e) {
        float v = zp[(d4 * 4 + e) * 1024];
        zn = fmaf(v, v, zn);
        d1 = fmaf(v, ca[e], d1);
        d2 = fmaf(v, cc[e], d2);
      }
    }
    float da = zn + cnf[ka] - 2.f * d1;
    float db = zn + cnf[kb] - 2.f * d2;
    int kwin; float dwin;
    if (da < db || (da == db && ka < kb)) { kwin = ka; dwin = da; }
    else { kwin = kb; dwin = db; }
    fidx[t] = kwin;
    d2min = dwin;
    atomicAdd((unsigned*)(ws + WS_COUNTS_B) + kwin, 1u);
  }
  #pragma unroll
  for (int o = 32; o > 0; o >>= 1) {
    rowent += __shfl_down(rowent, o);
    d2min += __shfl_down(d2min, o);
  }
  if (t == 0) {
    float* wsf = (float*)ws;
    int slot = b & 63;
    atomicAdd(&wsf[slot * 2], rowent);
    atomicAdd(&wsf[slot * 2 + 1], d2min);
  }
  __syncthreads();

  // ---- gather chosen codes via LDS (fp32), write transposed coalesced ----
  float* zl = (float*)smem;  // dbuf region dead now (4096 words used)
  for (int i = 0; i < 16; ++i) {
    int idx = t + i * 256;
    int r = idx >> 6, d = idx & 63;
    zl[qw(r, d)] = cb[fidx[r] * 64 + d];
  }
  __syncthreads();
  float* outz = out + bb * 65536 + p0;
  #pragma unroll
  for (int i = 0; i < 4; ++i) {
    int q = t + i * 256;
    int d = q >> 4, rq = q & 15, r = rq << 2;
    f32x4 v;
    v.x = zl[qw(r + 0, d)];
    v.y = zl[qw(r + 1, d)];
    v.z = zl[qw(r + 2, d)];
    v.w = zl[qw(r + 3, d)];
    *(f32x4*)&outz[d * 1024 + r] = v;
  }
}

__global__ __launch_bounds__(1024) void vq_finalize(const float* __restrict__ var_q,
                                                    char* __restrict__ ws,
                                                    float* __restrict__ out) {
  __shared__ float red[48];
  int t = threadIdx.x;
  const unsigned* counts = (const unsigned*)(ws + WS_COUNTS_B);
  const float* wsf = (const float*)ws;
  float avg = (float)counts[t] * (1.0f / 65536.0f);
  float term = avg * __logf(avg + 1e-7f);
  float pd = 0.f, pc = 0.f;
  if (t < 64) { pd = wsf[2 * t]; pc = wsf[2 * t + 1]; }
  #pragma unroll
  for (int o = 32; o > 0; o >>= 1) {
    term += __shfl_down(term, o);
    pd += __shfl_down(pd, o);
    pc += __shfl_down(pc, o);
  }
  int wv = t >> 6, lane = t & 63;
  if (lane == 0) { red[wv * 3] = term; red[wv * 3 + 1] = pd; red[wv * 3 + 2] = pc; }
  __syncthreads();
  if (t == 0) {
    float ts = 0.f, ps = 0.f, cs = 0.f;
    #pragma unroll
    for (int i = 0; i < 16; ++i) {
      ts += red[i * 3]; ps += red[i * 3 + 1]; cs += red[i * 3 + 2];
    }
    float w = 0.5f / fmaxf(var_q[0], 1e-10f);
    out[4194304] = ps / 64.f + w * cs / 64.f;
    out[4194305] = __expf(-ts);
  }
}

extern "C" void kernel_launch(void* const* d_in, const int* in_sizes, int n_in,
                              void* d_out, int out_size, void* d_ws, size_t ws_size,
                              hipStream_t stream) {
  const float* z = (const float*)d_in[0];
  const float* vq = (const float*)d_in[1];
  const float* cb = (const float*)d_in[2];
  float* out = (float*)d_out;
  char* ws = (char*)d_ws;

  hipMemsetAsync(d_ws, 0, WS_ZERO_B, stream);
  vq_prep<<<256, 256, 0, stream>>>(cb, ws);
  vq_main<<<1024, 256, 0, stream>>>(z, cb, vq, ws, out);
  vq_finalize<<<1, 1024, 0, stream>>>(vq, ws, out);
}

// Round 13
// 71.738 us; speedup vs baseline: 1.3472x; 1.0582x over previous
//
#include <hip/hip_runtime.h>

// Gaussian VQ forward, split-bf16 MFMA. R11 VERBATIM except: single-pass
// scoring (a_hi x c_hi only; the a_lo/c_lo compensation MFMAs deleted).
// Top-2 + exact fp32 rescore retained -> argmax exact unless BOTH bf16
// top-2 miss the true best (P~0). Controlled experiment vs R12's fail.
// bs=64, dim_z=64, W=H=32 -> N=65536 rows, K=1024 codes, D=64.
//
// ws layout (bytes) — identical to R3/R10/R11 (validated):
//   [0    ..  511] : 64 (kld_discrete, kld_continuous) partial pairs (float)
//   [512  .. 4607] : cnorm[1024] fp32
//   [4608 .. 8703] : counts[1024] uint
//   [8704 ..     ] : cb_hi bf16[1024][64]  (131072 B)
//   [139776 ..   ] : cb_lo bf16[1024][64]  (131072 B)
#define WS_CNORM_B  512
#define WS_COUNTS_B 4608
#define WS_CBHI_B   8704
#define WS_CBLO_B   139776
#define WS_ZERO_B   8704

typedef __attribute__((ext_vector_type(8))) short short8;
typedef __attribute__((ext_vector_type(4))) float f32x4;

__device__ __forceinline__ unsigned short f2bf(float x) {
  unsigned u = __builtin_bit_cast(unsigned, x);
  u += 0x7fffu + ((u >> 16) & 1u);
  return (unsigned short)(u >> 16);
}
__device__ __forceinline__ float bf2f(unsigned short h) {
  unsigned u = ((unsigned)h) << 16;
  return __builtin_bit_cast(float, u);
}
__device__ __forceinline__ int qw(int r, int d) {
  return (r << 6) | (d ^ (r & 31));
}

// ---- prep: codebook -> bf16 hi/lo splits + ||c||^2 (verbatim R11) ----
__global__ __launch_bounds__(256) void vq_prep(const float* __restrict__ cb,
                                               char* __restrict__ ws) {
  int tid = blockIdx.x * 256 + threadIdx.x;
  int k = tid >> 6, d = threadIdx.x & 63;
  float v = cb[tid];
  unsigned short hi = f2bf(v);
  unsigned short lo = f2bf(v - bf2f(hi));
  ((unsigned short*)(ws + WS_CBHI_B))[tid] = hi;
  ((unsigned short*)(ws + WS_CBLO_B))[tid] = lo;
  float s = v * v;
  #pragma unroll
  for (int o = 32; o > 0; o >>= 1) s += __shfl_down(s, o);
  if (d == 0) ((float*)(ws + WS_CNORM_B))[k] = s;
}

// LDS map (bytes) — verbatim R11:
//   [0, 32768)      chunk dbuf (parity*16384; hi 8K | lo 8K each).
//                   Prologue: z hi [0,8192) / lo [8192,16384).
//                   Epilogue: fp32 gather buffer [0,16384).
//   [32768, 34048)  row state: 64 x {m, S1, S2, b1, b2} (20 B)
//   [34048, 34304)  fidx[64]
#define ST_OFF   32768
#define FIDX_OFF 34048

__global__ __launch_bounds__(256, 4) void vq_main(const float* __restrict__ z,
                                                  const float* __restrict__ cb,
                                                  const float* __restrict__ var_q,
                                                  char* __restrict__ ws,
                                                  float* __restrict__ out) {
  __shared__ __align__(16) char smem[34304];

  const int t = threadIdx.x;
  const int b = blockIdx.x;          // 1024 blocks, 64 rows each
  const int bb = b >> 4, p0 = (b & 15) << 6;
  const int l = t & 63, wv = t >> 6;           // 4 waves
  const int lg = l >> 4, lr = l & 15;
  const float w = 0.5f / fmaxf(var_q[0], 1e-10f);
  const float w2 = 2.f * w;
  const float nw = -w;

  // ---- stage z (64 rows) -> [0,8K) hi, [8K,16K) lo, swizzled [p][d] ----
  for (int i = 0; i < 8; ++i) {
    int idx = t + i * 256;             // 2048 u32 slots: p(64) x d2(32)
    int d2 = idx >> 6, p = idx & 63;
    float v0 = z[bb * 65536 + (2 * d2) * 1024 + p0 + p];
    float v1 = z[bb * 65536 + (2 * d2 + 1) * 1024 + p0 + p];
    unsigned short h0 = f2bf(v0), h1 = f2bf(v1);
    unsigned short o0 = f2bf(v0 - bf2f(h0)), o1 = f2bf(v1 - bf2f(h1));
    int byte = (p * 128 + d2 * 4) ^ ((p & 7) << 4);
    *(unsigned*)(smem + byte) = ((unsigned)h1 << 16) | h0;
    *(unsigned*)(smem + 8192 + byte) = ((unsigned)o1 << 16) | o0;
  }
  __syncthreads();

  // ---- A fragments: wave's 16 rows (row = wv*16 + lr) ----
  short8 a_hi[2], a_lo[2];
  {
    int row = wv * 16 + lr;
    #pragma unroll
    for (int ks = 0; ks < 2; ++ks) {
      int byte = (row * 128 + ks * 64 + lg * 16) ^ ((row & 7) << 4);
      a_hi[ks] = *(const short8*)(smem + byte);
      a_lo[ks] = *(const short8*)(smem + 8192 + byte);
    }
  }
  __syncthreads();  // z reads done; region becomes chunk dbuf

  // ---- prologue: stage chunk 0 (64 codes: 8KB hi + 8KB lo) into parity 0 ----
  const char* cbh = ws + WS_CBHI_B;
  const char* cbl = ws + WS_CBLO_B;
  {
    #pragma unroll
    for (int pas = 0; pas < 2; ++pas) {
      int o = t + pas * 256;
      int dst = (o * 16) ^ (((o >> 3) & 7) << 4);
      *(f32x4*)(smem + dst) = *(const f32x4*)(cbh + o * 16);
      *(f32x4*)(smem + 8192 + dst) = *(const f32x4*)(cbl + o * 16);
    }
  }
  __syncthreads();

  // per-lane state: 4 rows (row = wv*16 + lg*4 + j).
  // b1/b2 PACKED (R10-validated): low 10 mantissa bits cleared, code OR'd in.
  float m[4], S1[4], S2[4], b1[4], b2[4];
  #pragma unroll
  for (int j = 0; j < 4; ++j) {
    m[j] = -1e30f; S1[j] = 0.f; S2[j] = 0.f; b1[j] = -1e30f; b2[j] = -1e30f;
  }

  const float* cnf = (const float*)(ws + WS_CNORM_B);

  for (int ch = 0; ch < 16; ++ch) {
    char* cur = smem + (ch & 1) * 16384;
    char* nxt = smem + ((ch + 1) & 1) * 16384;
    f32x4 rh0, rh1, rl0, rl1;
    const bool pf = ch < 15;
    if (pf) {  // prefetch next chunk into regs; latency hides under compute
      const char* sh = cbh + (ch + 1) * 8192 + t * 16;
      const char* sl = cbl + (ch + 1) * 8192 + t * 16;
      rh0 = *(const f32x4*)sh;  rh1 = *(const f32x4*)(sh + 4096);
      rl0 = *(const f32x4*)sl;  rl1 = *(const f32x4*)(sl + 4096);
    }
    float cn2[4];
    #pragma unroll
    for (int ct = 0; ct < 4; ++ct) cn2[ct] = nw * cnf[ch * 64 + ct * 16 + lr];

    f32x4 acc[4];
    #pragma unroll
    for (int ct = 0; ct < 4; ++ct) {
      f32x4 a = {};
      #pragma unroll
      for (int ks = 0; ks < 2; ++ks) {
        int cr = ct * 16 + lr;
        int byte = (cr * 128 + ks * 64 + lg * 16) ^ ((cr & 7) << 4);
        short8 bh = *(const short8*)(cur + byte);
        // SINGLE-PASS: a_lo*bh and a_hi*bo compensation MFMAs deleted (the
        // one change vs R11). bo load removed with them (would be dead).
        a = __builtin_amdgcn_mfma_f32_16x16x32_bf16(a_hi[ks], bh, a, 0, 0, 0);
      }
      acc[ct] = a;
    }

    // epilogue: online-max rescale + packed fmax top-2 (verbatim R11)
    #pragma unroll
    for (int j = 0; j < 4; ++j) {
      float lv[4];
      #pragma unroll
      for (int ct = 0; ct < 4; ++ct) lv[ct] = fmaf(acc[ct][j], w2, cn2[ct]);
      float lm = fmaxf(fmaxf(lv[0], lv[1]), fmaxf(lv[2], lv[3]));
      float mn = fmaxf(m[j], lm);
      float sc = __expf(m[j] - mn);
      S1[j] *= sc; S2[j] *= sc; m[j] = mn;
      #pragma unroll
      for (int ct = 0; ct < 4; ++ct) {
        float x = lv[ct];
        unsigned ku = (unsigned)(ch * 64 + ct * 16 + lr);
        unsigned xb = (__builtin_bit_cast(unsigned, x) & ~1023u) | ku;
        float xp = __builtin_bit_cast(float, xb);
        float tm = fminf(b1[j], xp);
        b1[j] = fmaxf(b1[j], xp);
        b2[j] = fmaxf(b2[j], tm);
        float e = __expf(x - mn);
        S1[j] += e;
        S2[j] = fmaf(x, e, S2[j]);   // S2 = sum x * e^{x-m}
      }
    }

    if (pf) {
      #pragma unroll
      for (int pas = 0; pas < 2; ++pas) {
        int o = t + pas * 256;
        int dst = (o * 16) ^ (((o >> 3) & 7) << 4);
        *(f32x4*)(nxt + dst) = pas ? rh1 : rh0;
        *(f32x4*)(nxt + 8192 + dst) = pas ? rl1 : rl0;
      }
    }
    __syncthreads();
  }

  // ---- merge the 16 code-columns within each wave (verbatim R11) ----
  #pragma unroll
  for (int st = 1; st < 16; st <<= 1) {
    #pragma unroll
    for (int j = 0; j < 4; ++j) {
      float om = __shfl_xor(m[j], st);
      float o1 = __shfl_xor(S1[j], st);
      float o2 = __shfl_xor(S2[j], st);
      float ov1 = __shfl_xor(b1[j], st);
      float ov2 = __shfl_xor(b2[j], st);
      float mn = fmaxf(m[j], om);
      float sa = __expf(m[j] - mn), sb = __expf(om - mn);
      S1[j] = sa * S1[j] + sb * o1;
      S2[j] = sa * S2[j] + sb * o2;
      m[j] = mn;
      float nb1 = fmaxf(b1[j], ov1);
      float nb2 = fmaxf(fminf(b1[j], ov1), fmaxf(b2[j], ov2));
      b1[j] = nb1; b2[j] = nb2;
    }
  }

  // ---- state write: 64 rows x 20 B (verbatim R11) ----
  float* stw = (float*)(smem + ST_OFF);
  if (lr == 0) {
    #pragma unroll
    for (int j = 0; j < 4; ++j) {
      int r = wv * 16 + lg * 4 + j;
      float* p = stw + r * 5;
      p[0] = m[j]; p[1] = S1[j]; p[2] = S2[j]; p[3] = b1[j]; p[4] = b2[j];
    }
  }
  __syncthreads();

  // ---- per-row tail (wave 0): entropy + exact fp32 top-2 rescore ----
  int* fidx = (int*)(smem + FIDX_OFF);
  float rowent = 0.f, d2min = 0.f;
  if (t < 64) {
    const float* p = stw + t * 5;
    float mn = p[0], s1 = p[1], s2 = p[2];
    int ka = (int)(__builtin_bit_cast(unsigned, p[3]) & 1023u);
    int kb = (int)(__builtin_bit_cast(unsigned, p[4]) & 1023u);
    rowent = (s2 - mn * s1) / s1 - __logf(s1);
    const float* zp = z + bb * 65536 + p0 + t;
    const float* c1p = cb + ka * 64;
    const float* c2p = cb + kb * 64;
    float zn = 0.f, d1 = 0.f, d2 = 0.f;
    #pragma unroll 4
    for (int d4 = 0; d4 < 16; ++d4) {
      f32x4 ca = *(const f32x4*)(c1p + d4 * 4);
      f32x4 cc = *(const f32x4*)(c2p + d4 * 4);
      #pragma unroll
      for (int e = 0; e < 4; ++e) {
        float v = zp[(d4 * 4 + e) * 1024];
        zn = fmaf(v, v, zn);
        d1 = fmaf(v, ca[e], d1);
        d2 = fmaf(v, cc[e], d2);
      }
    }
    float da = zn + cnf[ka] - 2.f * d1;
    float db = zn + cnf[kb] - 2.f * d2;
    int kwin; float dwin;
    if (da < db || (da == db && ka < kb)) { kwin = ka; dwin = da; }
    else { kwin = kb; dwin = db; }
    fidx[t] = kwin;
    d2min = dwin;
    atomicAdd((unsigned*)(ws + WS_COUNTS_B) + kwin, 1u);
  }
  #pragma unroll
  for (int o = 32; o > 0; o >>= 1) {
    rowent += __shfl_down(rowent, o);
    d2min += __shfl_down(d2min, o);
  }
  if (t == 0) {
    float* wsf = (float*)ws;
    int slot = b & 63;
    atomicAdd(&wsf[slot * 2], rowent);
    atomicAdd(&wsf[slot * 2 + 1], d2min);
  }
  __syncthreads();

  // ---- gather chosen codes via LDS (fp32), write transposed coalesced ----
  float* zl = (float*)smem;  // dbuf region dead now (4096 words used)
  for (int i = 0; i < 16; ++i) {
    int idx = t + i * 256;
    int r = idx >> 6, d = idx & 63;
    zl[qw(r, d)] = cb[fidx[r] * 64 + d];
  }
  __syncthreads();
  float* outz = out + bb * 65536 + p0;
  #pragma unroll
  for (int i = 0; i < 4; ++i) {
    int q = t + i * 256;
    int d = q >> 4, rq = q & 15, r = rq << 2;
    f32x4 v;
    v.x = zl[qw(r + 0, d)];
    v.y = zl[qw(r + 1, d)];
    v.z = zl[qw(r + 2, d)];
    v.w = zl[qw(r + 3, d)];
    *(f32x4*)&outz[d * 1024 + r] = v;
  }
}

__global__ __launch_bounds__(1024) void vq_finalize(const float* __restrict__ var_q,
                                                    char* __restrict__ ws,
                                                    float* __restrict__ out) {
  __shared__ float red[48];
  int t = threadIdx.x;
  const unsigned* counts = (const unsigned*)(ws + WS_COUNTS_B);
  const float* wsf = (const float*)ws;
  float avg = (float)counts[t] * (1.0f / 65536.0f);
  float term = avg * __logf(avg + 1e-7f);
  float pd = 0.f, pc = 0.f;
  if (t < 64) { pd = wsf[2 * t]; pc = wsf[2 * t + 1]; }
  #pragma unroll
  for (int o = 32; o > 0; o >>= 1) {
    term += __shfl_down(term, o);
    pd += __shfl_down(pd, o);
    pc += __shfl_down(pc, o);
  }
  int wv = t >> 6, lane = t & 63;
  if (lane == 0) { red[wv * 3] = term; red[wv * 3 + 1] = pd; red[wv * 3 + 2] = pc; }
  __syncthreads();
  if (t == 0) {
    float ts = 0.f, ps = 0.f, cs = 0.f;
    #pragma unroll
    for (int i = 0; i < 16; ++i) {
      ts += red[i * 3]; ps += red[i * 3 + 1]; cs += red[i * 3 + 2];
    }
    float w = 0.5f / fmaxf(var_q[0], 1e-10f);
    out[4194304] = ps / 64.f + w * cs / 64.f;
    out[4194305] = __expf(-ts);
  }
}

extern "C" void kernel_launch(void* const* d_in, const int* in_sizes, int n_in,
                              void* d_out, int out_size, void* d_ws, size_t ws_size,
                              hipStream_t stream) {
  const float* z = (const float*)d_in[0];
  const float* vq = (const float*)d_in[1];
  const float* cb = (const float*)d_in[2];
  float* out = (float*)d_out;
  char* ws = (char*)d_ws;

  hipMemsetAsync(d_ws, 0, WS_ZERO_B, stream);
  vq_prep<<<256, 256, 0, stream>>>(cb, ws);
  vq_main<<<1024, 256, 0, stream>>>(z, cb, vq, ws, out);
  vq_finalize<<<1, 1024, 0, stream>>>(vq, ws, out);
}